// Round 8
// baseline (347.385 us; speedup 1.0000x reference)
//
#include <hip/hip_runtime.h>
#include <hip/hip_bf16.h>

// B=16, S=2048, D=64 attention w/ symmetric pad mask.
// out = [context (B*S*D fp32), attn (B*S*S fp32)] concatenated.
//
// R12: operand-swapped QK^T (P computed transposed). Pass-B LDS-pipe audit of
// R11 showed ~540cy/panel/wave: 32 scalar ds_write_u16 P-writes + 8 b64 attn
// re-reads dominated. Swapping the MFMA operands (MFMA16(kb,qa), SAME frags,
// m89 layout algebra) yields lane(g,c) reg r = P[q-row c][k-col jt*16+g*4+r]:
//  - attn stored DIRECTLY from acc as one f32x4 NT store per jt (fp32-exact,
//    no LDS round trip, no bf2f unpacking);
//  - P->LDS becomes one ds_write_b64 (short4) per jt (was 4x ds_write_u16);
//    PV A-frag read (sPw + c*PROWP + ks*32 + g*8) unchanged byte-for-byte;
//  - PV interleaved per-ks (P[ks] ready after jts 2ks,2ks+1; same-wave LDS
//    ordering, no barrier), V frags prefetched one ks ahead and issued BEFORE
//    that ks's stores so V vmcnt-waits never force a store drain (FIFO);
//  - pass A: scalar per-lane rsum + 2-step shfl_xor(16/32) reduce; scv is a
//    per-lane scalar (q-row c).
// Kept from R11: gload_lds K staging w/ dbuf (pass A 1 barrier/panel, pass B
// 2-phase 1 barrier/panel), packed wave-order Vp (R10-verified), XCD swizzle,
// bf16 LDS mask (b64 reads), NT stores, Q prescale 1/8, 3 blocks/CU.
// Fallback R4 kernel retained.
#define NBATCH 16
#define SLEN   2048
#define DIM    64
#define TQ     64
#define NTHR   256
#define NW     4
#define PANEL  128
#define NPANEL (SLEN / PANEL)   // 16
#define PROWP  136              // shorts: 128 data + 8 pad
// fallback (R4) layout constants
#define PROWK  72
#define PROWV  136

typedef __attribute__((ext_vector_type(8))) short bf16x8;
typedef __attribute__((ext_vector_type(4))) float f32x4;

__device__ inline short f2bf(float f) {
    union { __hip_bfloat16 h; short s; } u;
    u.h = __float2bfloat16(f);
    return u.s;
}
__device__ inline float bf2f(unsigned short s) {
    union { unsigned u; float f; } x;
    x.u = ((unsigned)s) << 16;
    return x.f;
}
__device__ inline bf16x8 pack8(float4 a, float4 b) {
    bf16x8 r;
    r[0] = f2bf(a.x); r[1] = f2bf(a.y); r[2] = f2bf(a.z); r[3] = f2bf(a.w);
    r[4] = f2bf(b.x); r[5] = f2bf(b.y); r[6] = f2bf(b.z); r[7] = f2bf(b.w);
    return r;
}
__device__ inline bf16x8 pack8s(float4 a, float4 b, float s) {
    bf16x8 r;
    r[0] = f2bf(a.x * s); r[1] = f2bf(a.y * s); r[2] = f2bf(a.z * s); r[3] = f2bf(a.w * s);
    r[4] = f2bf(b.x * s); r[5] = f2bf(b.y * s); r[6] = f2bf(b.z * s); r[7] = f2bf(b.w * s);
    return r;
}

// ---------------- pre-pass ------------------------------------------------
// Kws (R8 layout, verified): row j's 8 16B-blocks stored at blk ^ (j&7).
// Vp (R10 layout, verified): per panel p, [i=ks*4+nt 0..15][lane 0..63][8sh]
//   lane(g,c) elem e <-> V[p*128 + ks*32 + g*8 + e][nt*16 + c]  (V^T frag)
__global__ __launch_bounds__(256) void preconvert_kernel(
    const float* __restrict__ K, const float* __restrict__ V,
    short* __restrict__ Kws, short* __restrict__ Vp)
{
    const int b  = blockIdx.x >> 4;      // NPANEL=16
    const int p  = blockIdx.x & 15;
    const int j0 = p * PANEL;
    const int tid = threadIdx.x;
    const float* Kb = K + ((size_t)b * SLEN + j0) * DIM;
    const float* Vb = V + ((size_t)b * SLEN + j0) * DIM;
    short* Kwb = Kws + ((size_t)b * SLEN + j0) * DIM;
    short* Vpb = Vp  + (size_t)b * SLEN * DIM + (size_t)p * 8192;

    #pragma unroll
    for (int it = 0; it < 8; it++) {           // K: 128 rows x 16 float4
        const int idx = it * 256 + tid;
        const int row = idx >> 4, c4 = idx & 15;
        float4 kv = *(const float4*)(Kb + (size_t)row * DIM + c4 * 4);
        const int blk = (c4 >> 1) ^ (row & 7); // natural block c4>>1, swizzled
        *(short4*)(Kwb + (size_t)row * DIM + blk * 8 + (c4 & 1) * 4) =
            make_short4(f2bf(kv.x), f2bf(kv.y), f2bf(kv.z), f2bf(kv.w));
    }
    #pragma unroll
    for (int it = 0; it < 2; it++) {           // V: 4k x 4d register transpose
        const int task = it * 256 + tid;
        const int kb = (task >> 4) * 4, d4 = (task & 15) * 4;
        const float* vp = Vb + (size_t)kb * DIM + d4;
        float4 r0 = *(const float4*)(vp);
        float4 r1 = *(const float4*)(vp + DIM);
        float4 r2 = *(const float4*)(vp + 2 * DIM);
        float4 r3 = *(const float4*)(vp + 3 * DIM);
        const int ks = (kb >> 5) & 3, gg = (kb >> 3) & 3, e = kb & 7;
        #define VDST(dd) (Vpb + ((size_t)((ks * 4 + ((d4 + dd) >> 4)) * 64 \
                              + gg * 16 + ((d4 + dd) & 15))) * 8 + e)
        *(short4*)VDST(0) = make_short4(f2bf(r0.x), f2bf(r1.x), f2bf(r2.x), f2bf(r3.x));
        *(short4*)VDST(1) = make_short4(f2bf(r0.y), f2bf(r1.y), f2bf(r2.y), f2bf(r3.y));
        *(short4*)VDST(2) = make_short4(f2bf(r0.z), f2bf(r1.z), f2bf(r2.z), f2bf(r3.z));
        *(short4*)VDST(3) = make_short4(f2bf(r0.w), f2bf(r1.w), f2bf(r2.w), f2bf(r3.w));
        #undef VDST
    }
}

// ---- async staging: linear LDS copy (swizzle already in global layout) ----
__device__ __forceinline__ void stage_k_panel(const short* __restrict__ Kwb, int j0,
                                              short* sdst, int w, int l) {
    const short* src = Kwb + (size_t)j0 * DIM + w * 512 + l * 8;  // per-lane
    short* dst = sdst + w * 512;                                  // wave-uniform
    #pragma unroll
    for (int i = 0; i < 4; i++)
        __builtin_amdgcn_global_load_lds((const unsigned int*)(src + i * 2048),
                                         (unsigned int*)(dst + i * 2048), 16, 0, 0);
}

#define MFMA16(a, bb, cc) __builtin_amdgcn_mfma_f32_16x16x32_bf16((a), (bb), (cc), 0, 0, 0)

__global__ __launch_bounds__(NTHR, 3) void sdpa_kernel(
    const float* __restrict__ Q, const short* __restrict__ Kws,
    const short* __restrict__ Vp, const int* __restrict__ M,
    float* __restrict__ outCtx, float* __restrict__ outAttn)
{
    __shared__ __align__(16) short sK0[PANEL * DIM];    // 16 KB K buffer 0
    __shared__ __align__(16) short sK1[PANEL * DIM];    // 16 KB K buffer 1
    __shared__ __align__(16) short sP[NW * 16 * PROWP]; // 17 KB per-wave P
    __shared__ short sMaskBf[SLEN];                     // 4 KB bf16 0/1 col mask

    const int tid = threadIdx.x;
    const int w = tid >> 6, l = tid & 63, g = l >> 4, c = l & 15;
    // bijective XCD swizzle: 512 blocks % 8 XCDs == 0 -> simple form.
    const int wg = (blockIdx.x & 7) * (NBATCH * (SLEN / TQ) / 8) + (blockIdx.x >> 3);
    const int b  = wg >> 5;                  // 32 blocks/batch
    const int i0 = (wg & 31) * TQ;
    const int i0w = i0 + w * 16;

    const short* Kwb = Kws + (size_t)b * SLEN * DIM;
    const short* Vwb = Vp  + (size_t)b * SLEN * DIM;
    const int*   Mb  = M + b * SLEN;

    // Q A-frags, pre-scaled by 1/sqrt(64)=2^-3 (exact; bit-identical scores)
    bf16x8 qa0, qa1;
    {
        const float* qp = Q + ((size_t)b * SLEN + i0w + c) * DIM + g * 8;
        qa0 = pack8s(*(const float4*)(qp),      *(const float4*)(qp + 4),  0.125f);
        qa1 = pack8s(*(const float4*)(qp + 32), *(const float4*)(qp + 36), 0.125f);
    }

    stage_k_panel(Kwb, 0, sK0, w, l);
    // mask -> LDS once (bf16 1.0/0.0); lgkmcnt path only thereafter
    #pragma unroll
    for (int i = 0; i < 8; i++) {
        const int idx = i * NTHR + tid;
        sMaskBf[idx] = Mb[idx] ? (short)0 : (short)0x3F80;
    }
    __syncthreads();

    // ---- Pass A: row sums (swapped MFMA: lane holds P[c][jt*16+g*4+r]) ----
    float rsum = 0.f;
    for (int p = 0; p < NPANEL; p++) {
        const short* cur = (p & 1) ? sK1 : sK0;
        if (p < NPANEL - 1)
            stage_k_panel(Kwb, (p + 1) * PANEL, (p & 1) ? sK0 : sK1, w, l);
        const int j0 = p * PANEL;
        #pragma unroll
        for (int jt = 0; jt < 8; jt++) {
            const short* kr = cur + (jt * 16 + c) * DIM;
            bf16x8 kb0 = *(const bf16x8*)(kr + ((g ^ (c & 7)) * 8));
            bf16x8 kb1 = *(const bf16x8*)(kr + (((g + 4) ^ (c & 7)) * 8));
            f32x4 acc = {0.f, 0.f, 0.f, 0.f};
            acc = MFMA16(kb0, qa0, acc);   // swapped: D = P^T tile
            acc = MFMA16(kb1, qa1, acc);
            short4 m4 = *(const short4*)(sMaskBf + j0 + jt * 16 + g * 4);
            rsum += __expf(acc[0]) * bf2f((unsigned short)m4.x)
                  + __expf(acc[1]) * bf2f((unsigned short)m4.y)
                  + __expf(acc[2]) * bf2f((unsigned short)m4.z)
                  + __expf(acc[3]) * bf2f((unsigned short)m4.w);
        }
        __syncthreads();   // drains next-panel stage (flew under compute)
    }

    // issue pass-B initial K stage; latency hides under the reduce
    stage_k_panel(Kwb, 0, sK0, w, l);

    rsum += __shfl_xor(rsum, 16, 64);      // combine g-groups (xor bits 4,5)
    rsum += __shfl_xor(rsum, 32, 64);
    const bool rm = sMaskBf[i0w + c] == 0; // this lane's q-row masked?
    const float scv = (rm || rsum <= 0.f) ? 0.f : 1.f / rsum;

    // ---- Pass B: 2-phase, ONE barrier per panel ----
    short* sPw = sP + w * 16 * PROWP;
    f32x4 pv[4];
    #pragma unroll
    for (int nt = 0; nt < 4; nt++) pv[nt] = (f32x4){0.f, 0.f, 0.f, 0.f};

    __syncthreads();   // K0 staged and visible

    for (int p = 0; p < NPANEL; p++) {
        const int j0 = p * PANEL;
        if (p < NPANEL - 1)
            stage_k_panel(Kwb, j0 + PANEL, (p & 1) ? sK0 : sK1, w, l);
        const short* kbuf = (p & 1) ? sK1 : sK0;
        const short* vb = Vwb + (size_t)p * 8192 + l * 8;

        // V frags for ks=0, issued before any of this panel's stores
        bf16x8 vc0 = *(const bf16x8*)(vb);
        bf16x8 vc1 = *(const bf16x8*)(vb + 512);
        bf16x8 vc2 = *(const bf16x8*)(vb + 1024);
        bf16x8 vc3 = *(const bf16x8*)(vb + 1536);

        const size_t rowB = ((size_t)b * SLEN + i0w + c) * SLEN + j0;

        #pragma unroll
        for (int ks = 0; ks < 4; ks++) {
            // prefetch next ks's V BEFORE this ks's stores (FIFO: V older
            // than stores -> V-waits never force a store drain)
            bf16x8 vn0, vn1, vn2, vn3;
            if (ks < 3) {
                const short* vnb = vb + (ks + 1) * 2048;
                vn0 = *(const bf16x8*)(vnb);
                vn1 = *(const bf16x8*)(vnb + 512);
                vn2 = *(const bf16x8*)(vnb + 1024);
                vn3 = *(const bf16x8*)(vnb + 1536);
            }
            #pragma unroll
            for (int jj = 0; jj < 2; jj++) {
                const int jt = ks * 2 + jj;
                const short* kr = kbuf + (jt * 16 + c) * DIM;
                bf16x8 kb0 = *(const bf16x8*)(kr + ((g ^ (c & 7)) * 8));
                bf16x8 kb1 = *(const bf16x8*)(kr + (((g + 4) ^ (c & 7)) * 8));
                f32x4 acc = {0.f, 0.f, 0.f, 0.f};
                acc = MFMA16(kb0, qa0, acc);   // swapped
                acc = MFMA16(kb1, qa1, acc);
                short4 m4 = *(const short4*)(sMaskBf + j0 + jt * 16 + g * 4);
                f32x4 pr;
                pr[0] = __expf(acc[0]) * bf2f((unsigned short)m4.x) * scv;
                pr[1] = __expf(acc[1]) * bf2f((unsigned short)m4.y) * scv;
                pr[2] = __expf(acc[2]) * bf2f((unsigned short)m4.z) * scv;
                pr[3] = __expf(acc[3]) * bf2f((unsigned short)m4.w) * scv;
                // attn: 4 consecutive cols of row (i0w+c) -> one f32x4 NT store
                __builtin_nontemporal_store(pr,
                    (f32x4*)(outAttn + rowB + jt * 16 + g * 4));
                // P bf16 -> per-wave LDS (vectorized b64 write, row = c)
                *(short4*)(sPw + c * PROWP + jt * 16 + g * 4) =
                    make_short4(f2bf(pr[0]), f2bf(pr[1]), f2bf(pr[2]), f2bf(pr[3]));
            }
            // PV for this ks (P[ks] complete; same-wave LDS ordering)
            bf16x8 af = *(const bf16x8*)(sPw + c * PROWP + ks * 32 + g * 8);
            pv[0] = MFMA16(af, vc0, pv[0]);
            pv[1] = MFMA16(af, vc1, pv[1]);
            pv[2] = MFMA16(af, vc2, pv[2]);
            pv[3] = MFMA16(af, vc3, pv[3]);
            if (ks < 3) { vc0 = vn0; vc1 = vn1; vc2 = vn2; vc3 = vn3; }
        }
        __syncthreads();   // single per-panel drain: stage + stores
    }

    // ctx write: C-layout direct store (pre-normalized P => no further scale)
    #pragma unroll
    for (int nt = 0; nt < 4; nt++) {
        #pragma unroll
        for (int r = 0; r < 4; r++)
            __builtin_nontemporal_store(pv[nt][r],
                outCtx + ((size_t)b * SLEN + i0w + g * 4 + r) * DIM + nt * 16 + c);
    }
}

// ---------------- fallback: verified R4 kernel (used if ws too small) -----
__global__ __launch_bounds__(NTHR, 3) void sdpa_kernel_fb(
    const float* __restrict__ Q, const float* __restrict__ K,
    const float* __restrict__ V, const int* __restrict__ M,
    float* __restrict__ outCtx, float* __restrict__ outAttn)
{
    __shared__ __align__(16) short sK[128 * PROWK];
    __shared__ __align__(16) short sVT[64 * PROWV];
    __shared__ __align__(16) short sP[NW * 16 * PROWP];
    __shared__ float sMask[PANEL];

    const int tid = threadIdx.x;
    const int w = tid >> 6, l = tid & 63, g = l >> 4, c = l & 15;
    const int b  = blockIdx.x >> 5;
    const int i0 = (blockIdx.x & 31) * TQ;
    const int i0w = i0 + w * 16;

    const float* Kb = K + (size_t)b * SLEN * DIM;
    const float* Vb = V + (size_t)b * SLEN * DIM;
    const int*   Mb = M + b * SLEN;

    bf16x8 qa0, qa1;
    {
        const float* qp = Q + ((size_t)b * SLEN + i0w + c) * DIM + g * 8;
        qa0 = pack8(*(const float4*)(qp),      *(const float4*)(qp + 4));
        qa1 = pack8(*(const float4*)(qp + 32), *(const float4*)(qp + 36));
    }

    const float scl = 0.125f;
    float rsum[4] = {0.f, 0.f, 0.f, 0.f};

    for (int p = 0; p < NPANEL; p++) {
        const int j0 = p * PANEL;
        #pragma unroll
        for (int it = 0; it < 8; it++) {
            const int idx = it * NTHR + tid;
            const int row = idx >> 4, c4 = idx & 15;
            float4 kv = *(const float4*)(Kb + (size_t)(j0 + row) * DIM + c4 * 4);
            *(short4*)(sK + row * PROWK + c4 * 4) =
                make_short4(f2bf(kv.x), f2bf(kv.y), f2bf(kv.z), f2bf(kv.w));
        }
        if (tid < PANEL) sMask[tid] = Mb[j0 + tid] ? 0.f : 1.f;
        __syncthreads();
        #pragma unroll
        for (int jt = 0; jt < 8; jt++) {
            const short* kr = sK + (jt * 16 + c) * PROWK + g * 8;
            bf16x8 kb0 = *(const bf16x8*)(kr);
            bf16x8 kb1 = *(const bf16x8*)(kr + 32);
            f32x4 acc = {0.f, 0.f, 0.f, 0.f};
            acc = MFMA16(qa0, kb0, acc);
            acc = MFMA16(qa1, kb1, acc);
            const float em = sMask[jt * 16 + c];
            #pragma unroll
            for (int r = 0; r < 4; r++)
                rsum[r] += __expf(acc[r] * scl) * em;
        }
        __syncthreads();
    }
    #pragma unroll
    for (int off = 1; off < 16; off <<= 1) {
        #pragma unroll
        for (int r = 0; r < 4; r++)
            rsum[r] += __shfl_xor(rsum[r], off, 64);
    }
    float scv[4];
    #pragma unroll
    for (int r = 0; r < 4; r++) {
        const int rm = Mb[i0w + g * 4 + r];
        scv[r] = (rm || rsum[r] <= 0.f) ? 0.f : 1.f / rsum[r];
    }

    short* sPw = sP + w * 16 * PROWP;
    f32x4 pv[4];
    #pragma unroll
    for (int nt = 0; nt < 4; nt++) pv[nt] = (f32x4){0.f, 0.f, 0.f, 0.f};

    for (int p = 0; p < NPANEL; p++) {
        const int j0 = p * PANEL;
        #pragma unroll
        for (int it = 0; it < 8; it++) {
            const int idx = it * NTHR + tid;
            const int row = idx >> 4, c4 = idx & 15;
            float4 kv = *(const float4*)(Kb + (size_t)(j0 + row) * DIM + c4 * 4);
            *(short4*)(sK + row * PROWK + c4 * 4) =
                make_short4(f2bf(kv.x), f2bf(kv.y), f2bf(kv.z), f2bf(kv.w));
        }
        #pragma unroll
        for (int it = 0; it < 2; it++) {
            const int task = it * NTHR + tid;
            const int k4 = task >> 4, d4g = task & 15;
            const int kb = k4 * 4, d4 = d4g * 4;
            const int colb = kb ^ ((d4g & 3) << 3);
            const float* vp = Vb + (size_t)(j0 + kb) * DIM + d4;
            float4 r0 = *(const float4*)(vp);
            float4 r1 = *(const float4*)(vp + DIM);
            float4 r2 = *(const float4*)(vp + 2 * DIM);
            float4 r3 = *(const float4*)(vp + 3 * DIM);
            *(short4*)(sVT + (d4 + 0) * PROWV + colb) =
                make_short4(f2bf(r0.x), f2bf(r1.x), f2bf(r2.x), f2bf(r3.x));
            *(short4*)(sVT + (d4 + 1) * PROWV + colb) =
                make_short4(f2bf(r0.y), f2bf(r1.y), f2bf(r2.y), f2bf(r3.y));
            *(short4*)(sVT + (d4 + 2) * PROWV + colb) =
                make_short4(f2bf(r0.z), f2bf(r1.z), f2bf(r2.z), f2bf(r3.z));
            *(short4*)(sVT + (d4 + 3) * PROWV + colb) =
                make_short4(f2bf(r0.w), f2bf(r1.w), f2bf(r2.w), f2bf(r3.w));
        }
        if (tid < PANEL) sMask[tid] = Mb[j0 + tid] ? 0.f : 1.f;
        __syncthreads();

        #pragma unroll
        for (int jt = 0; jt < 8; jt++) {
            const short* kr = sK + (jt * 16 + c) * PROWK + g * 8;
            bf16x8 kb0 = *(const bf16x8*)(kr);
            bf16x8 kb1 = *(const bf16x8*)(kr + 32);
            f32x4 acc = {0.f, 0.f, 0.f, 0.f};
            acc = MFMA16(qa0, kb0, acc);
            acc = MFMA16(qa1, kb1, acc);
            const float em = sMask[jt * 16 + c];
            #pragma unroll
            for (int r = 0; r < 4; r++)
                sPw[(g * 4 + r) * PROWP + jt * 16 + c] =
                    f2bf(__expf(acc[r] * scl) * em * scv[r]);
        }
        #pragma unroll
        for (int ks = 0; ks < 4; ks++) {
            bf16x8 af = *(const bf16x8*)(sPw + c * PROWP + ks * 32 + g * 8);
            #pragma unroll
            for (int nt = 0; nt < 4; nt++) {
                const int d = nt * 16 + c;
                const int gp = g ^ ((d >> 2) & 3);
                bf16x8 bfrag = *(const bf16x8*)(sVT + d * PROWV + ks * 32 + gp * 8);
                pv[nt] = MFMA16(af, bfrag, pv[nt]);
            }
        }
        const size_t rowBase = (size_t)b * SLEN + i0w;
        #pragma unroll
        for (int it = 0; it < 8; it++) {
            const int idx = it * 64 + l;
            const int row = idx >> 5, col4 = idx & 31;
            const unsigned short* pp = (const unsigned short*)sPw + row * PROWP + col4 * 4;
            ushort4 p4 = *(const ushort4*)(pp);
            float4 o = {bf2f(p4.x), bf2f(p4.y), bf2f(p4.z), bf2f(p4.w)};
            *(float4*)(outAttn + (rowBase + row) * SLEN + j0 + col4 * 4) = o;
        }
        __syncthreads();
    }

    #pragma unroll
    for (int nt = 0; nt < 4; nt++) {
        #pragma unroll
        for (int r = 0; r < 4; r++)
            outCtx[((size_t)b * SLEN + i0w + g * 4 + r) * DIM + nt * 16 + c] = pv[nt][r];
    }
}

extern "C" void kernel_launch(void* const* d_in, const int* in_sizes, int n_in,
                              void* d_out, int out_size, void* d_ws, size_t ws_size,
                              hipStream_t stream) {
    const float* Q = (const float*)d_in[0];
    const float* K = (const float*)d_in[1];
    const float* V = (const float*)d_in[2];
    const int*   M = (const int*)d_in[3];
    float* outCtx  = (float*)d_out;
    float* outAttn = (float*)d_out + (size_t)NBATCH * SLEN * DIM;
    dim3 grid(NBATCH * (SLEN / TQ));   // 512 blocks

    const size_t nElem = (size_t)NBATCH * SLEN * DIM;      // 2,097,152
    const size_t wsNeed = nElem * 2 * sizeof(short);       // 8 MB
    if (d_ws != nullptr && ws_size >= wsNeed) {
        short* Kws = (short*)d_ws;
        short* Vpp = Kws + nElem;
        preconvert_kernel<<<dim3(NBATCH * NPANEL), 256, 0, stream>>>(K, V, Kws, Vpp);
        sdpa_kernel<<<grid, NTHR, 0, stream>>>(Q, Kws, Vpp, M, outCtx, outAttn);
    } else {
        sdpa_kernel_fb<<<grid, NTHR, 0, stream>>>(Q, K, V, M, outCtx, outAttn);
    }
}

// Round 9
// 315.151 us; speedup vs baseline: 1.1023x; 1.1023x over previous
//
#include <hip/hip_runtime.h>
#include <hip/hip_bf16.h>

// B=16, S=2048, D=64 attention w/ symmetric pad mask.
// out = [context (B*S*D fp32), attn (B*S*S fp32)] concatenated.
//
// R13: R12's swapped-MFMA + R11's coalesced attn store path.
// R12 post-mortem: storing attn straight from the swapped accumulator
// scattered each wave-store across 16 rows x 64B (8KB stride) -> destroyed
// write coalescing on the 256MB stream (-36us). But R12's other changes are
// real wins that don't touch the store: P->LDS is one ds_write_b64 per jt
// (R11: 4 scalar ds_write_u16), softmax state is one scalar per lane, pass-A
// reduce is 2 shfls. P lands in LDS in R11's exact row-major layout, so
// R11's 1KB-coalesced copy-out loop is reused unchanged, and the PV A-frag
// read is byte-identical. PV interleaved per-ks, V frags prefetched BEFORE
// each ks's (now only LDS) writes; stores drain once per panel.
// Kept: gload_lds K staging w/ dbuf (1 barrier/panel both passes), packed
// wave-order Vp, XCD swizzle, bf16 LDS mask, NT stores, Q prescale 1/8,
// 3 blocks/CU. Fallback R4 kernel retained.
#define NBATCH 16
#define SLEN   2048
#define DIM    64
#define TQ     64
#define NTHR   256
#define NW     4
#define PANEL  128
#define NPANEL (SLEN / PANEL)   // 16
#define PROWP  136              // shorts: 128 data + 8 pad
// fallback (R4) layout constants
#define PROWK  72
#define PROWV  136

typedef __attribute__((ext_vector_type(8))) short bf16x8;
typedef __attribute__((ext_vector_type(4))) float f32x4;

__device__ inline short f2bf(float f) {
    union { __hip_bfloat16 h; short s; } u;
    u.h = __float2bfloat16(f);
    return u.s;
}
__device__ inline float bf2f(unsigned short s) {
    union { unsigned u; float f; } x;
    x.u = ((unsigned)s) << 16;
    return x.f;
}
__device__ inline bf16x8 pack8(float4 a, float4 b) {
    bf16x8 r;
    r[0] = f2bf(a.x); r[1] = f2bf(a.y); r[2] = f2bf(a.z); r[3] = f2bf(a.w);
    r[4] = f2bf(b.x); r[5] = f2bf(b.y); r[6] = f2bf(b.z); r[7] = f2bf(b.w);
    return r;
}
__device__ inline bf16x8 pack8s(float4 a, float4 b, float s) {
    bf16x8 r;
    r[0] = f2bf(a.x * s); r[1] = f2bf(a.y * s); r[2] = f2bf(a.z * s); r[3] = f2bf(a.w * s);
    r[4] = f2bf(b.x * s); r[5] = f2bf(b.y * s); r[6] = f2bf(b.z * s); r[7] = f2bf(b.w * s);
    return r;
}

// ---------------- pre-pass ------------------------------------------------
// Kws (R8 layout, verified): row j's 8 16B-blocks stored at blk ^ (j&7).
// Vp (R10 layout, verified): per panel p, [i=ks*4+nt 0..15][lane 0..63][8sh]
//   lane(g,c) elem e <-> V[p*128 + ks*32 + g*8 + e][nt*16 + c]  (V^T frag)
__global__ __launch_bounds__(256) void preconvert_kernel(
    const float* __restrict__ K, const float* __restrict__ V,
    short* __restrict__ Kws, short* __restrict__ Vp)
{
    const int b  = blockIdx.x >> 4;      // NPANEL=16
    const int p  = blockIdx.x & 15;
    const int j0 = p * PANEL;
    const int tid = threadIdx.x;
    const float* Kb = K + ((size_t)b * SLEN + j0) * DIM;
    const float* Vb = V + ((size_t)b * SLEN + j0) * DIM;
    short* Kwb = Kws + ((size_t)b * SLEN + j0) * DIM;
    short* Vpb = Vp  + (size_t)b * SLEN * DIM + (size_t)p * 8192;

    #pragma unroll
    for (int it = 0; it < 8; it++) {           // K: 128 rows x 16 float4
        const int idx = it * 256 + tid;
        const int row = idx >> 4, c4 = idx & 15;
        float4 kv = *(const float4*)(Kb + (size_t)row * DIM + c4 * 4);
        const int blk = (c4 >> 1) ^ (row & 7); // natural block c4>>1, swizzled
        *(short4*)(Kwb + (size_t)row * DIM + blk * 8 + (c4 & 1) * 4) =
            make_short4(f2bf(kv.x), f2bf(kv.y), f2bf(kv.z), f2bf(kv.w));
    }
    #pragma unroll
    for (int it = 0; it < 2; it++) {           // V: 4k x 4d register transpose
        const int task = it * 256 + tid;
        const int kb = (task >> 4) * 4, d4 = (task & 15) * 4;
        const float* vp = Vb + (size_t)kb * DIM + d4;
        float4 r0 = *(const float4*)(vp);
        float4 r1 = *(const float4*)(vp + DIM);
        float4 r2 = *(const float4*)(vp + 2 * DIM);
        float4 r3 = *(const float4*)(vp + 3 * DIM);
        const int ks = (kb >> 5) & 3, gg = (kb >> 3) & 3, e = kb & 7;
        #define VDST(dd) (Vpb + ((size_t)((ks * 4 + ((d4 + dd) >> 4)) * 64 \
                              + gg * 16 + ((d4 + dd) & 15))) * 8 + e)
        *(short4*)VDST(0) = make_short4(f2bf(r0.x), f2bf(r1.x), f2bf(r2.x), f2bf(r3.x));
        *(short4*)VDST(1) = make_short4(f2bf(r0.y), f2bf(r1.y), f2bf(r2.y), f2bf(r3.y));
        *(short4*)VDST(2) = make_short4(f2bf(r0.z), f2bf(r1.z), f2bf(r2.z), f2bf(r3.z));
        *(short4*)VDST(3) = make_short4(f2bf(r0.w), f2bf(r1.w), f2bf(r2.w), f2bf(r3.w));
        #undef VDST
    }
}

// ---- async staging: linear LDS copy (swizzle already in global layout) ----
__device__ __forceinline__ void stage_k_panel(const short* __restrict__ Kwb, int j0,
                                              short* sdst, int w, int l) {
    const short* src = Kwb + (size_t)j0 * DIM + w * 512 + l * 8;  // per-lane
    short* dst = sdst + w * 512;                                  // wave-uniform
    #pragma unroll
    for (int i = 0; i < 4; i++)
        __builtin_amdgcn_global_load_lds((const unsigned int*)(src + i * 2048),
                                         (unsigned int*)(dst + i * 2048), 16, 0, 0);
}

#define MFMA16(a, bb, cc) __builtin_amdgcn_mfma_f32_16x16x32_bf16((a), (bb), (cc), 0, 0, 0)

__global__ __launch_bounds__(NTHR, 3) void sdpa_kernel(
    const float* __restrict__ Q, const short* __restrict__ Kws,
    const short* __restrict__ Vp, const int* __restrict__ M,
    float* __restrict__ outCtx, float* __restrict__ outAttn)
{
    __shared__ __align__(16) short sK0[PANEL * DIM];    // 16 KB K buffer 0
    __shared__ __align__(16) short sK1[PANEL * DIM];    // 16 KB K buffer 1
    __shared__ __align__(16) short sP[NW * 16 * PROWP]; // 17 KB per-wave P
    __shared__ short sMaskBf[SLEN];                     // 4 KB bf16 0/1 col mask

    const int tid = threadIdx.x;
    const int w = tid >> 6, l = tid & 63, g = l >> 4, c = l & 15;
    // bijective XCD swizzle: 512 blocks % 8 XCDs == 0 -> simple form.
    const int wg = (blockIdx.x & 7) * (NBATCH * (SLEN / TQ) / 8) + (blockIdx.x >> 3);
    const int b  = wg >> 5;                  // 32 blocks/batch
    const int i0 = (wg & 31) * TQ;
    const int i0w = i0 + w * 16;

    const short* Kwb = Kws + (size_t)b * SLEN * DIM;
    const short* Vwb = Vp  + (size_t)b * SLEN * DIM;
    const int*   Mb  = M + b * SLEN;

    // Q A-frags, pre-scaled by 1/sqrt(64)=2^-3 (exact; bit-identical scores)
    bf16x8 qa0, qa1;
    {
        const float* qp = Q + ((size_t)b * SLEN + i0w + c) * DIM + g * 8;
        qa0 = pack8s(*(const float4*)(qp),      *(const float4*)(qp + 4),  0.125f);
        qa1 = pack8s(*(const float4*)(qp + 32), *(const float4*)(qp + 36), 0.125f);
    }

    stage_k_panel(Kwb, 0, sK0, w, l);
    // mask -> LDS once (bf16 1.0/0.0); lgkmcnt path only thereafter
    #pragma unroll
    for (int i = 0; i < 8; i++) {
        const int idx = i * NTHR + tid;
        sMaskBf[idx] = Mb[idx] ? (short)0 : (short)0x3F80;
    }
    __syncthreads();

    // ---- Pass A: row sums (swapped MFMA: lane holds P[c][jt*16+g*4+r]) ----
    float rsum = 0.f;
    for (int p = 0; p < NPANEL; p++) {
        const short* cur = (p & 1) ? sK1 : sK0;
        if (p < NPANEL - 1)
            stage_k_panel(Kwb, (p + 1) * PANEL, (p & 1) ? sK0 : sK1, w, l);
        const int j0 = p * PANEL;
        #pragma unroll
        for (int jt = 0; jt < 8; jt++) {
            const short* kr = cur + (jt * 16 + c) * DIM;
            bf16x8 kb0 = *(const bf16x8*)(kr + ((g ^ (c & 7)) * 8));
            bf16x8 kb1 = *(const bf16x8*)(kr + (((g + 4) ^ (c & 7)) * 8));
            f32x4 acc = {0.f, 0.f, 0.f, 0.f};
            acc = MFMA16(kb0, qa0, acc);   // swapped: D = P^T tile
            acc = MFMA16(kb1, qa1, acc);
            short4 m4 = *(const short4*)(sMaskBf + j0 + jt * 16 + g * 4);
            rsum += __expf(acc[0]) * bf2f((unsigned short)m4.x)
                  + __expf(acc[1]) * bf2f((unsigned short)m4.y)
                  + __expf(acc[2]) * bf2f((unsigned short)m4.z)
                  + __expf(acc[3]) * bf2f((unsigned short)m4.w);
        }
        __syncthreads();   // drains next-panel stage (flew under compute)
    }

    // issue pass-B initial K stage; latency hides under the reduce
    stage_k_panel(Kwb, 0, sK0, w, l);

    rsum += __shfl_xor(rsum, 16, 64);      // combine g-groups
    rsum += __shfl_xor(rsum, 32, 64);
    const bool rm = sMaskBf[i0w + c] == 0; // this lane's q-row masked?
    const float scv = (rm || rsum <= 0.f) ? 0.f : 1.f / rsum;

    // ---- Pass B: 2-phase, ONE barrier per panel ----
    short* sPw = sP + w * 16 * PROWP;
    f32x4 pv[4];
    #pragma unroll
    for (int nt = 0; nt < 4; nt++) pv[nt] = (f32x4){0.f, 0.f, 0.f, 0.f};

    __syncthreads();   // K0 staged and visible

    for (int p = 0; p < NPANEL; p++) {
        const int j0 = p * PANEL;
        if (p < NPANEL - 1)
            stage_k_panel(Kwb, j0 + PANEL, (p & 1) ? sK0 : sK1, w, l);
        const short* kbuf = (p & 1) ? sK1 : sK0;
        const short* vb = Vwb + (size_t)p * 8192 + l * 8;

        // V frags for ks=0
        bf16x8 vc0 = *(const bf16x8*)(vb);
        bf16x8 vc1 = *(const bf16x8*)(vb + 512);
        bf16x8 vc2 = *(const bf16x8*)(vb + 1024);
        bf16x8 vc3 = *(const bf16x8*)(vb + 1536);

        #pragma unroll
        for (int ks = 0; ks < 4; ks++) {
            bf16x8 vn0, vn1, vn2, vn3;
            if (ks < 3) {          // prefetch next ks's V
                const short* vnb = vb + (ks + 1) * 2048;
                vn0 = *(const bf16x8*)(vnb);
                vn1 = *(const bf16x8*)(vnb + 512);
                vn2 = *(const bf16x8*)(vnb + 1024);
                vn3 = *(const bf16x8*)(vnb + 1536);
            }
            #pragma unroll
            for (int jj = 0; jj < 2; jj++) {
                const int jt = ks * 2 + jj;
                const short* kr = kbuf + (jt * 16 + c) * DIM;
                bf16x8 kb0 = *(const bf16x8*)(kr + ((g ^ (c & 7)) * 8));
                bf16x8 kb1 = *(const bf16x8*)(kr + (((g + 4) ^ (c & 7)) * 8));
                f32x4 acc = {0.f, 0.f, 0.f, 0.f};
                acc = MFMA16(kb0, qa0, acc);   // swapped
                acc = MFMA16(kb1, qa1, acc);
                short4 m4 = *(const short4*)(sMaskBf + j0 + jt * 16 + g * 4);
                // P bf16 -> per-wave LDS: ONE b64 write per jt (row-major
                // layout identical to R11's sPw; feeds PV A-frag + copy-out)
                *(short4*)(sPw + c * PROWP + jt * 16 + g * 4) = make_short4(
                    f2bf(__expf(acc[0]) * bf2f((unsigned short)m4.x) * scv),
                    f2bf(__expf(acc[1]) * bf2f((unsigned short)m4.y) * scv),
                    f2bf(__expf(acc[2]) * bf2f((unsigned short)m4.z) * scv),
                    f2bf(__expf(acc[3]) * bf2f((unsigned short)m4.w) * scv));
            }
            // PV for this ks (P[ks] complete; same-wave lgkmcnt ordering)
            bf16x8 af = *(const bf16x8*)(sPw + c * PROWP + ks * 32 + g * 8);
            pv[0] = MFMA16(af, vc0, pv[0]);
            pv[1] = MFMA16(af, vc1, pv[1]);
            pv[2] = MFMA16(af, vc2, pv[2]);
            pv[3] = MFMA16(af, vc3, pv[3]);
            if (ks < 3) { vc0 = vn0; vc1 = vn1; vc2 = vn2; vc3 = vn3; }
        }

        // attn write: 16 rows x 32 float4, fully coalesced (R11 path)
        const size_t rowBase = (size_t)b * SLEN + i0w;
        #pragma unroll
        for (int it = 0; it < 8; it++) {
            const int idx = it * 64 + l;
            const int row = idx >> 5, col4 = idx & 31;
            const unsigned short* pp = (const unsigned short*)sPw + row * PROWP + col4 * 4;
            ushort4 p4 = *(const ushort4*)(pp);
            f32x4 o = {bf2f(p4.x), bf2f(p4.y), bf2f(p4.z), bf2f(p4.w)};
            __builtin_nontemporal_store(o,
                (f32x4*)(outAttn + (rowBase + row) * SLEN + j0 + col4 * 4));
        }
        __syncthreads();   // single per-panel drain: stage + stores
    }

    // ctx write: C-layout direct store (pre-normalized P => no further scale)
    #pragma unroll
    for (int nt = 0; nt < 4; nt++) {
        #pragma unroll
        for (int r = 0; r < 4; r++)
            __builtin_nontemporal_store(pv[nt][r],
                outCtx + ((size_t)b * SLEN + i0w + g * 4 + r) * DIM + nt * 16 + c);
    }
}

// ---------------- fallback: verified R4 kernel (used if ws too small) -----
__global__ __launch_bounds__(NTHR, 3) void sdpa_kernel_fb(
    const float* __restrict__ Q, const float* __restrict__ K,
    const float* __restrict__ V, const int* __restrict__ M,
    float* __restrict__ outCtx, float* __restrict__ outAttn)
{
    __shared__ __align__(16) short sK[128 * PROWK];
    __shared__ __align__(16) short sVT[64 * PROWV];
    __shared__ __align__(16) short sP[NW * 16 * PROWP];
    __shared__ float sMask[PANEL];

    const int tid = threadIdx.x;
    const int w = tid >> 6, l = tid & 63, g = l >> 4, c = l & 15;
    const int b  = blockIdx.x >> 5;
    const int i0 = (blockIdx.x & 31) * TQ;
    const int i0w = i0 + w * 16;

    const float* Kb = K + (size_t)b * SLEN * DIM;
    const float* Vb = V + (size_t)b * SLEN * DIM;
    const int*   Mb = M + b * SLEN;

    bf16x8 qa0, qa1;
    {
        const float* qp = Q + ((size_t)b * SLEN + i0w + c) * DIM + g * 8;
        qa0 = pack8(*(const float4*)(qp),      *(const float4*)(qp + 4));
        qa1 = pack8(*(const float4*)(qp + 32), *(const float4*)(qp + 36));
    }

    const float scl = 0.125f;
    float rsum[4] = {0.f, 0.f, 0.f, 0.f};

    for (int p = 0; p < NPANEL; p++) {
        const int j0 = p * PANEL;
        #pragma unroll
        for (int it = 0; it < 8; it++) {
            const int idx = it * NTHR + tid;
            const int row = idx >> 4, c4 = idx & 15;
            float4 kv = *(const float4*)(Kb + (size_t)(j0 + row) * DIM + c4 * 4);
            *(short4*)(sK + row * PROWK + c4 * 4) =
                make_short4(f2bf(kv.x), f2bf(kv.y), f2bf(kv.z), f2bf(kv.w));
        }
        if (tid < PANEL) sMask[tid] = Mb[j0 + tid] ? 0.f : 1.f;
        __syncthreads();
        #pragma unroll
        for (int jt = 0; jt < 8; jt++) {
            const short* kr = sK + (jt * 16 + c) * PROWK + g * 8;
            bf16x8 kb0 = *(const bf16x8*)(kr);
            bf16x8 kb1 = *(const bf16x8*)(kr + 32);
            f32x4 acc = {0.f, 0.f, 0.f, 0.f};
            acc = MFMA16(qa0, kb0, acc);
            acc = MFMA16(qa1, kb1, acc);
            const float em = sMask[jt * 16 + c];
            #pragma unroll
            for (int r = 0; r < 4; r++)
                rsum[r] += __expf(acc[r] * scl) * em;
        }
        __syncthreads();
    }
    #pragma unroll
    for (int off = 1; off < 16; off <<= 1) {
        #pragma unroll
        for (int r = 0; r < 4; r++)
            rsum[r] += __shfl_xor(rsum[r], off, 64);
    }
    float scv[4];
    #pragma unroll
    for (int r = 0; r < 4; r++) {
        const int rm = Mb[i0w + g * 4 + r];
        scv[r] = (rm || rsum[r] <= 0.f) ? 0.f : 1.f / rsum[r];
    }

    short* sPw = sP + w * 16 * PROWP;
    f32x4 pv[4];
    #pragma unroll
    for (int nt = 0; nt < 4; nt++) pv[nt] = (f32x4){0.f, 0.f, 0.f, 0.f};

    for (int p = 0; p < NPANEL; p++) {
        const int j0 = p * PANEL;
        #pragma unroll
        for (int it = 0; it < 8; it++) {
            const int idx = it * NTHR + tid;
            const int row = idx >> 4, c4 = idx & 15;
            float4 kv = *(const float4*)(Kb + (size_t)(j0 + row) * DIM + c4 * 4);
            *(short4*)(sK + row * PROWK + c4 * 4) =
                make_short4(f2bf(kv.x), f2bf(kv.y), f2bf(kv.z), f2bf(kv.w));
        }
        #pragma unroll
        for (int it = 0; it < 2; it++) {
            const int task = it * NTHR + tid;
            const int k4 = task >> 4, d4g = task & 15;
            const int kb = k4 * 4, d4 = d4g * 4;
            const int colb = kb ^ ((d4g & 3) << 3);
            const float* vp = Vb + (size_t)(j0 + kb) * DIM + d4;
            float4 r0 = *(const float4*)(vp);
            float4 r1 = *(const float4*)(vp + DIM);
            float4 r2 = *(const float4*)(vp + 2 * DIM);
            float4 r3 = *(const float4*)(vp + 3 * DIM);
            *(short4*)(sVT + (d4 + 0) * PROWV + colb) =
                make_short4(f2bf(r0.x), f2bf(r1.x), f2bf(r2.x), f2bf(r3.x));
            *(short4*)(sVT + (d4 + 1) * PROWV + colb) =
                make_short4(f2bf(r0.y), f2bf(r1.y), f2bf(r2.y), f2bf(r3.y));
            *(short4*)(sVT + (d4 + 2) * PROWV + colb) =
                make_short4(f2bf(r0.z), f2bf(r1.z), f2bf(r2.z), f2bf(r3.z));
            *(short4*)(sVT + (d4 + 3) * PROWV + colb) =
                make_short4(f2bf(r0.w), f2bf(r1.w), f2bf(r2.w), f2bf(r3.w));
        }
        if (tid < PANEL) sMask[tid] = Mb[j0 + tid] ? 0.f : 1.f;
        __syncthreads();

        #pragma unroll
        for (int jt = 0; jt < 8; jt++) {
            const short* kr = sK + (jt * 16 + c) * PROWK + g * 8;
            bf16x8 kb0 = *(const bf16x8*)(kr);
            bf16x8 kb1 = *(const bf16x8*)(kr + 32);
            f32x4 acc = {0.f, 0.f, 0.f, 0.f};
            acc = MFMA16(qa0, kb0, acc);
            acc = MFMA16(qa1, kb1, acc);
            const float em = sMask[jt * 16 + c];
            #pragma unroll
            for (int r = 0; r < 4; r++)
                sPw[(g * 4 + r) * PROWP + jt * 16 + c] =
                    f2bf(__expf(acc[r] * scl) * em * scv[r]);
        }
        #pragma unroll
        for (int ks = 0; ks < 4; ks++) {
            bf16x8 af = *(const bf16x8*)(sPw + c * PROWP + ks * 32 + g * 8);
            #pragma unroll
            for (int nt = 0; nt < 4; nt++) {
                const int d = nt * 16 + c;
                const int gp = g ^ ((d >> 2) & 3);
                bf16x8 bfrag = *(const bf16x8*)(sVT + d * PROWV + ks * 32 + gp * 8);
                pv[nt] = MFMA16(af, bfrag, pv[nt]);
            }
        }
        const size_t rowBase = (size_t)b * SLEN + i0w;
        #pragma unroll
        for (int it = 0; it < 8; it++) {
            const int idx = it * 64 + l;
            const int row = idx >> 5, col4 = idx & 31;
            const unsigned short* pp = (const unsigned short*)sPw + row * PROWP + col4 * 4;
            ushort4 p4 = *(const ushort4*)(pp);
            float4 o = {bf2f(p4.x), bf2f(p4.y), bf2f(p4.z), bf2f(p4.w)};
            *(float4*)(outAttn + (rowBase + row) * SLEN + j0 + col4 * 4) = o;
        }
        __syncthreads();
    }

    #pragma unroll
    for (int nt = 0; nt < 4; nt++) {
        #pragma unroll
        for (int r = 0; r < 4; r++)
            outCtx[((size_t)b * SLEN + i0w + g * 4 + r) * DIM + nt * 16 + c] = pv[nt][r];
    }
}

extern "C" void kernel_launch(void* const* d_in, const int* in_sizes, int n_in,
                              void* d_out, int out_size, void* d_ws, size_t ws_size,
                              hipStream_t stream) {
    const float* Q = (const float*)d_in[0];
    const float* K = (const float*)d_in[1];
    const float* V = (const float*)d_in[2];
    const int*   M = (const int*)d_in[3];
    float* outCtx  = (float*)d_out;
    float* outAttn = (float*)d_out + (size_t)NBATCH * SLEN * DIM;
    dim3 grid(NBATCH * (SLEN / TQ));   // 512 blocks

    const size_t nElem = (size_t)NBATCH * SLEN * DIM;      // 2,097,152
    const size_t wsNeed = nElem * 2 * sizeof(short);       // 8 MB
    if (d_ws != nullptr && ws_size >= wsNeed) {
        short* Kws = (short*)d_ws;
        short* Vpp = Kws + nElem;
        preconvert_kernel<<<dim3(NBATCH * NPANEL), 256, 0, stream>>>(K, V, Kws, Vpp);
        sdpa_kernel<<<grid, NTHR, 0, stream>>>(Q, Kws, Vpp, M, outCtx, outAttn);
    } else {
        sdpa_kernel_fb<<<grid, NTHR, 0, stream>>>(Q, K, V, M, outCtx, outAttn);
    }
}